// Round 1
// baseline (1416.416 us; speedup 1.0000x reference)
//
#include <hip/hip_runtime.h>

#define NCH 9   // 8 eigvec channels + 1 degree channel

// ---------- tiny weight precompute: w012, P, Q (64 each) ----------
__global__ void smallvec_k(const float* __restrict__ W0, const float* __restrict__ b0,
                           const float* __restrict__ W1, const float* __restrict__ b1,
                           const float* __restrict__ W2a, float* __restrict__ SV) {
  __shared__ float w01[64], g[64];
  int j = threadIdx.x;
  float a = 0.f, bg = 0.f;
  for (int i = 0; i < 64; ++i) { float w = W1[i*64 + j]; a += W0[i]*w; bg += b0[i]*w; }
  w01[j] = a; g[j] = bg;
  __syncthreads();
  float w012 = 0.f, P = 0.f, Q = 0.f;
  for (int i = 0; i < 64; ++i) { float w = W2a[i*64 + j]; w012 += w01[i]*w; P += g[i]*w; Q += b1[i]*w; }
  SV[j] = w012; SV[64 + j] = P; SV[128 + j] = Q;
}

// ---------- B1 init: [pos (nan->0), 1.0] ----------
__global__ void init1_k(const float* __restrict__ eig, float* __restrict__ B1, int N) {
  int n = blockIdx.x * blockDim.x + threadIdx.x;
  if (n >= N) return;
  const float* sr = eig + (size_t)n * 8;
  float* o = B1 + (size_t)n * NCH;
  #pragma unroll
  for (int k = 0; k < 8; ++k) { float v = sr[k]; o[k] = (v != v) ? 0.f : v; }
  o[8] = 1.f;
}

// ---------- edge pass 1: B1[dst] += [pos[src], 1] ----------
__global__ void edge1_k(const int* __restrict__ ei, const float* __restrict__ eig,
                        float* __restrict__ B1, int E) {
  int e = blockIdx.x * blockDim.x + threadIdx.x;
  if (e >= E) return;
  int s = ei[e], d = ei[E + e];
  const float* sr = eig + (size_t)s * 8;
  float* orow = B1 + (size_t)d * NCH;
  #pragma unroll
  for (int k = 0; k < 8; ++k) { float v = sr[k]; v = (v != v) ? 0.f : v; unsafeAtomicAdd(orow + k, v); }
  unsafeAtomicAdd(orow + 8, 1.f);
}

// ---------- generic copy (self-term init for next agg) ----------
__global__ void copy_k(const float* __restrict__ a, float* __restrict__ b, int tot) {
  int i = blockIdx.x * blockDim.x + threadIdx.x;
  if (i < tot) b[i] = a[i];
}

// ---------- generic edge pass: Bout[dst] += Bin[src] ----------
__global__ void edge_k(const int* __restrict__ ei, const float* __restrict__ Bin,
                       float* __restrict__ Bout, int E) {
  int e = blockIdx.x * blockDim.x + threadIdx.x;
  if (e >= E) return;
  int s = ei[e], d = ei[E + e];
  const float* sr = Bin + (size_t)s * NCH;
  float* orow = Bout + (size_t)d * NCH;
  #pragma unroll
  for (int k = 0; k < NCH; ++k) unsafeAtomicAdd(orow + k, sr[k]);
}

// ---------- fused PE + rho: one wave per node ----------
__global__ __launch_bounds__(256) void pe_k(
    const float* __restrict__ B1, const float* __restrict__ B2, const float* __restrict__ B3,
    const float* __restrict__ SV, const float* __restrict__ b2a,
    const float* __restrict__ W2b, const float* __restrict__ b2b,
    const float* __restrict__ Wr1, const float* __restrict__ br1,
    const float* __restrict__ Wr2, const float* __restrict__ br2,
    float* __restrict__ out, int N) {
  __shared__ float vbuf[4][8][64];
  __shared__ float pebuf[4][128];
  __shared__ float zbuf[4][64];
  int wid  = threadIdx.x >> 6;
  int lane = threadIdx.x & 63;
  int n = blockIdx.x * 4 + wid;
  bool active = (n < N);
  float d1 = 0.f, d2 = 0.f;
  if (active) { d1 = B1[(size_t)n*NCH + 8]; d2 = B2[(size_t)n*NCH + 8]; }
  float w012 = SV[lane], P = SV[64 + lane], Q = SV[128 + lane];
  float Ej = d2 * P + d1 * Q + b2a[lane];
  if (active) {
    #pragma unroll
    for (int k = 0; k < 8; ++k) {
      float s = B3[(size_t)n*NCH + k];
      float t = s * w012;
      vbuf[wid][k][lane] = fmaxf(t + Ej, 0.f) + fmaxf(Ej - t, 0.f);
    }
  }
  __syncthreads();
  // pe_raw[c] for c = lane, lane+64   (c = k*16 + o)
  if (active) {
    #pragma unroll
    for (int cc = 0; cc < 2; ++cc) {
      int c = lane + cc * 64;
      int k = c >> 4, o = c & 15;
      float acc = 2.f * b2b[o];
      #pragma unroll 8
      for (int j = 0; j < 64; ++j) acc += vbuf[wid][k][j] * W2b[j*16 + o];
      pebuf[wid][c] = acc;
    }
  }
  __syncthreads();
  // rho layer 1: z[h] = relu(pe @ Wr1 + br1)
  float acc = br1[lane];
  if (active) {
    #pragma unroll 8
    for (int c = 0; c < 128; ++c) acc += pebuf[wid][c] * Wr1[c*64 + lane];
    zbuf[wid][lane] = fmaxf(acc, 0.f);
  }
  __syncthreads();
  // rho layer 2 -> out[:, 112:128]
  if (active && lane < 16) {
    float acc2 = br2[lane];
    #pragma unroll 8
    for (int h = 0; h < 64; ++h) acc2 += zbuf[wid][h] * Wr2[h*16 + lane];
    out[(size_t)n*128 + 112 + lane] = acc2;
  }
}

// ---------- expand_x linear: out[:, 0:112] = x @ Wx + bx ----------
__global__ void x_k(const float* __restrict__ x, const float* __restrict__ Wx,
                    const float* __restrict__ bx, float* __restrict__ out, int total) {
  int idx = blockIdx.x * blockDim.x + threadIdx.x;
  if (idx >= total) return;
  int n = idx / 112, o = idx % 112;
  const float* xr = x + (size_t)n * 64;
  float acc = bx[o];
  #pragma unroll 8
  for (int i = 0; i < 64; ++i) acc += xr[i] * Wx[i*112 + o];
  out[(size_t)n*128 + o] = acc;
}

extern "C" void kernel_launch(void* const* d_in, const int* in_sizes, int n_in,
                              void* d_out, int out_size, void* d_ws, size_t ws_size,
                              hipStream_t stream) {
  const float* eig = (const float*)d_in[0];
  const float* x   = (const float*)d_in[1];
  const int*   ei  = (const int*)d_in[2];
  // d_in[3] = batch_index (unused by reference)
  const float* W0  = (const float*)d_in[4];
  const float* b0  = (const float*)d_in[5];
  const float* W1  = (const float*)d_in[6];
  const float* b1  = (const float*)d_in[7];
  const float* W2a = (const float*)d_in[8];
  const float* b2a = (const float*)d_in[9];
  const float* W2b = (const float*)d_in[10];
  const float* b2b = (const float*)d_in[11];
  const float* Wr1 = (const float*)d_in[12];
  const float* br1 = (const float*)d_in[13];
  const float* Wr2 = (const float*)d_in[14];
  const float* br2 = (const float*)d_in[15];
  const float* Wx  = (const float*)d_in[16];
  const float* bx  = (const float*)d_in[17];
  float* out = (float*)d_out;

  int N = in_sizes[0] / 8;
  int E = in_sizes[2] / 2;

  float* B1 = (float*)d_ws;
  float* B2 = B1 + (size_t)N * NCH;
  float* B3 = B2 + (size_t)N * NCH;
  float* SV = B3 + (size_t)N * NCH;

  int ethreads = 256, eblocks = (E + 255) / 256;
  int ntot = N * NCH, cblocks = (ntot + 255) / 256;

  smallvec_k<<<1, 64, 0, stream>>>(W0, b0, W1, b1, W2a, SV);
  init1_k<<<(N + 255) / 256, 256, 0, stream>>>(eig, B1, N);
  edge1_k<<<eblocks, ethreads, 0, stream>>>(ei, eig, B1, E);
  copy_k<<<cblocks, 256, 0, stream>>>(B1, B2, ntot);
  edge_k<<<eblocks, ethreads, 0, stream>>>(ei, B1, B2, E);
  copy_k<<<cblocks, 256, 0, stream>>>(B2, B3, ntot);
  edge_k<<<eblocks, ethreads, 0, stream>>>(ei, B2, B3, E);
  pe_k<<<(N + 3) / 4, 256, 0, stream>>>(B1, B2, B3, SV, b2a, W2b, b2b,
                                        Wr1, br1, Wr2, br2, out, N);
  x_k<<<(N * 112 + 255) / 256, 256, 0, stream>>>(x, Wx, bx, out, N * 112);
}

// Round 3
// 538.803 us; speedup vs baseline: 2.6288x; 2.6288x over previous
//
#include <hip/hip_runtime.h>

#define NCH 9   // 8 eigvec channels + 1 degree channel

// ---------- tiny weight precompute: w012, P, Q (64 each) ----------
__global__ void smallvec_k(const float* __restrict__ W0, const float* __restrict__ b0,
                           const float* __restrict__ W1, const float* __restrict__ b1,
                           const float* __restrict__ W2a, float* __restrict__ SV) {
  __shared__ float w01[64], g[64];
  int j = threadIdx.x;
  float a = 0.f, bg = 0.f;
  for (int i = 0; i < 64; ++i) { float w = W1[i*64 + j]; a += W0[i]*w; bg += b0[i]*w; }
  w01[j] = a; g[j] = bg;
  __syncthreads();
  float w012 = 0.f, P = 0.f, Q = 0.f;
  for (int i = 0; i < 64; ++i) { float w = W2a[i*64 + j]; w012 += w01[i]*w; P += g[i]*w; Q += b1[i]*w; }
  SV[j] = w012; SV[64 + j] = P; SV[128 + j] = Q;
}

// ---------- zero int buffer ----------
__global__ void zero_k(int* __restrict__ p, int n) {
  int i = blockIdx.x * blockDim.x + threadIdx.x;
  if (i < n) p[i] = 0;
}

// ---------- histogram of dst ----------
__global__ void hist_k(const int* __restrict__ ei, int* __restrict__ cnt, int E) {
  int e = blockIdx.x * blockDim.x + threadIdx.x;
  if (e < E) atomicAdd(&cnt[ei[E + e]], 1);
}

// ---------- single-block exclusive scan: cnt(in ptr) -> ptr, cursor copy ----------
__global__ void scan_k(int* __restrict__ ptr, int* __restrict__ cur, int N) {
  __shared__ int sums[256];
  int t = threadIdx.x;
  int chunk = (N + 255) / 256;
  int lo = t * chunk, hi = lo + chunk; if (hi > N) hi = N; if (lo > N) lo = N;
  int s = 0;
  for (int i = lo; i < hi; ++i) s += ptr[i];
  sums[t] = s;
  __syncthreads();
  // Hillis-Steele inclusive scan
  for (int off = 1; off < 256; off <<= 1) {
    int v = (t >= off) ? sums[t - off] : 0;
    __syncthreads();
    sums[t] += v;
    __syncthreads();
  }
  int run = sums[t] - s;   // exclusive prefix for this chunk
  for (int i = lo; i < hi; ++i) {
    int c = ptr[i];
    ptr[i] = run; cur[i] = run;
    run += c;
  }
  if (t == 255) ptr[N] = run;   // == E
}

// ---------- CSR fill: csr[cur[dst]++] = src ----------
__global__ void fill_k(const int* __restrict__ ei, int* __restrict__ cur,
                       int* __restrict__ csr, int E) {
  int e = blockIdx.x * blockDim.x + threadIdx.x;
  if (e >= E) return;
  int s = ei[e], d = ei[E + e];
  int pos = atomicAdd(&cur[d], 1);
  csr[pos] = s;
}

// ---------- agg pass 1 (from eigvecs, nan->0; ch8 = degree+1) ----------
__global__ void agg1_k(const int* __restrict__ ptr, const int* __restrict__ csr,
                       const float* __restrict__ eig, float* __restrict__ B1, int N) {
  int idx = blockIdx.x * blockDim.x + threadIdx.x;
  if (idx >= N * NCH) return;
  int n = idx / NCH, ch = idx % NCH;
  int lo = ptr[n], hi = ptr[n + 1];
  if (ch == 8) { B1[idx] = 1.f + (float)(hi - lo); return; }
  float v = eig[(size_t)n * 8 + ch]; v = (v != v) ? 0.f : v;
  float acc = v;
  int j = lo;
  for (; j + 4 <= hi; j += 4) {
    int s0 = csr[j], s1 = csr[j+1], s2 = csr[j+2], s3 = csr[j+3];
    float u0 = eig[(size_t)s0*8 + ch], u1 = eig[(size_t)s1*8 + ch];
    float u2 = eig[(size_t)s2*8 + ch], u3 = eig[(size_t)s3*8 + ch];
    u0 = (u0!=u0)?0.f:u0; u1 = (u1!=u1)?0.f:u1; u2 = (u2!=u2)?0.f:u2; u3 = (u3!=u3)?0.f:u3;
    acc += u0 + u1 + u2 + u3;
  }
  for (; j < hi; ++j) {
    int s = csr[j];
    float u = eig[(size_t)s*8 + ch]; u = (u!=u)?0.f:u;
    acc += u;
  }
  B1[idx] = acc;
}

// ---------- generic agg pass: Bout[n,ch] = Bin[n,ch] + sum_src Bin[src,ch] ----------
template<int CHO>
__global__ void agg_k(const int* __restrict__ ptr, const int* __restrict__ csr,
                      const float* __restrict__ Bin, float* __restrict__ Bout, int N) {
  int idx = blockIdx.x * blockDim.x + threadIdx.x;
  if (idx >= N * CHO) return;
  int n = idx / CHO, ch = idx % CHO;
  int lo = ptr[n], hi = ptr[n + 1];
  float acc = Bin[(size_t)n * NCH + ch];
  int j = lo;
  for (; j + 4 <= hi; j += 4) {
    int s0 = csr[j], s1 = csr[j+1], s2 = csr[j+2], s3 = csr[j+3];
    acc += Bin[(size_t)s0*NCH + ch] + Bin[(size_t)s1*NCH + ch]
         + Bin[(size_t)s2*NCH + ch] + Bin[(size_t)s3*NCH + ch];
  }
  for (; j < hi; ++j) acc += Bin[(size_t)csr[j]*NCH + ch];
  Bout[idx] = acc;
}

// ---------- fused PE + rho: one wave per node ----------
__global__ __launch_bounds__(256) void pe_k(
    const float* __restrict__ B1, const float* __restrict__ B2, const float* __restrict__ B3,
    const float* __restrict__ SV, const float* __restrict__ b2a,
    const float* __restrict__ W2b, const float* __restrict__ b2b,
    const float* __restrict__ Wr1, const float* __restrict__ br1,
    const float* __restrict__ Wr2, const float* __restrict__ br2,
    float* __restrict__ out, int N) {
  __shared__ float vbuf[4][8][64];
  __shared__ float pebuf[4][128];
  __shared__ float zbuf[4][64];
  int wid  = threadIdx.x >> 6;
  int lane = threadIdx.x & 63;
  int n = blockIdx.x * 4 + wid;
  bool active = (n < N);
  float d1 = 0.f, d2 = 0.f;
  if (active) { d1 = B1[(size_t)n*NCH + 8]; d2 = B2[(size_t)n*NCH + 8]; }
  float w012 = SV[lane], P = SV[64 + lane], Q = SV[128 + lane];
  float Ej = d2 * P + d1 * Q + b2a[lane];
  if (active) {
    #pragma unroll
    for (int k = 0; k < 8; ++k) {
      float s = B3[(size_t)n*8 + k];
      float t = s * w012;
      vbuf[wid][k][lane] = fmaxf(t + Ej, 0.f) + fmaxf(Ej - t, 0.f);
    }
  }
  __syncthreads();
  if (active) {
    #pragma unroll
    for (int cc = 0; cc < 2; ++cc) {
      int c = lane + cc * 64;
      int k = c >> 4, o = c & 15;
      float acc = 2.f * b2b[o];
      #pragma unroll 8
      for (int j = 0; j < 64; ++j) acc += vbuf[wid][k][j] * W2b[j*16 + o];
      pebuf[wid][c] = acc;
    }
  }
  __syncthreads();
  float acc = br1[lane];
  if (active) {
    #pragma unroll 8
    for (int c = 0; c < 128; ++c) acc += pebuf[wid][c] * Wr1[c*64 + lane];
    zbuf[wid][lane] = fmaxf(acc, 0.f);
  }
  __syncthreads();
  if (active && lane < 16) {
    float acc2 = br2[lane];
    #pragma unroll 8
    for (int h = 0; h < 64; ++h) acc2 += zbuf[wid][h] * Wr2[h*16 + lane];
    out[(size_t)n*128 + 112 + lane] = acc2;
  }
}

// ---------- expand_x linear: out[:, 0:112] = x @ Wx + bx ----------
__global__ void x_k(const float* __restrict__ x, const float* __restrict__ Wx,
                    const float* __restrict__ bx, float* __restrict__ out, int total) {
  int idx = blockIdx.x * blockDim.x + threadIdx.x;
  if (idx >= total) return;
  int n = idx / 112, o = idx % 112;
  const float* xr = x + (size_t)n * 64;
  float acc = bx[o];
  #pragma unroll 8
  for (int i = 0; i < 64; ++i) acc += xr[i] * Wx[i*112 + o];
  out[(size_t)n*128 + o] = acc;
}

extern "C" void kernel_launch(void* const* d_in, const int* in_sizes, int n_in,
                              void* d_out, int out_size, void* d_ws, size_t ws_size,
                              hipStream_t stream) {
  const float* eig = (const float*)d_in[0];
  const float* x   = (const float*)d_in[1];
  const int*   ei  = (const int*)d_in[2];
  const float* W0  = (const float*)d_in[4];
  const float* b0  = (const float*)d_in[5];
  const float* W1  = (const float*)d_in[6];
  const float* b1  = (const float*)d_in[7];
  const float* W2a = (const float*)d_in[8];
  const float* b2a = (const float*)d_in[9];
  const float* W2b = (const float*)d_in[10];
  const float* b2b = (const float*)d_in[11];
  const float* Wr1 = (const float*)d_in[12];
  const float* br1 = (const float*)d_in[13];
  const float* Wr2 = (const float*)d_in[14];
  const float* br2 = (const float*)d_in[15];
  const float* Wx  = (const float*)d_in[16];
  const float* bx  = (const float*)d_in[17];
  float* out = (float*)d_out;

  int N = in_sizes[0] / 8;
  int E = in_sizes[2] / 2;

  int*   ptr = (int*)d_ws;                 // N+1
  int*   cur = ptr + (N + 1);              // N
  int*   csr = cur + N;                    // E
  float* B1  = (float*)(csr + E);          // N*9
  float* B2  = B1 + (size_t)N * NCH;       // N*9
  float* B3  = B2 + (size_t)N * NCH;       // N*8
  float* SV  = B3 + (size_t)N * 8;         // 192

  int eblocks = (E + 255) / 256;

  zero_k<<<(N + 256) / 256, 256, 0, stream>>>(ptr, N + 1);
  hist_k<<<eblocks, 256, 0, stream>>>(ei, ptr, E);
  scan_k<<<1, 256, 0, stream>>>(ptr, cur, N);
  fill_k<<<eblocks, 256, 0, stream>>>(ei, cur, csr, E);

  smallvec_k<<<1, 64, 0, stream>>>(W0, b0, W1, b1, W2a, SV);

  agg1_k<<<(N * NCH + 255) / 256, 256, 0, stream>>>(ptr, csr, eig, B1, N);
  agg_k<NCH><<<(N * NCH + 255) / 256, 256, 0, stream>>>(ptr, csr, B1, B2, N);
  agg_k<8><<<(N * 8 + 255) / 256, 256, 0, stream>>>(ptr, csr, B2, B3, N);

  pe_k<<<(N + 3) / 4, 256, 0, stream>>>(B1, B2, B3, SV, b2a, W2b, b2b,
                                        Wr1, br1, Wr2, br2, out, N);
  x_k<<<(N * 112 + 255) / 256, 256, 0, stream>>>(x, Wx, bx, out, N * 112);
}